// Round 11
// baseline (50.591 us; speedup 1.0000x reference)
//
#include <hip/hip_runtime.h>

// WiSARD inference: B=4096, ENTRY=1024, TUPLE=16, CLASSES=10, NEURONS=64.
// out[b][c] = sum_n ram_bit[c][n][addr(b,c,n)]
//
//  1. packT : samples -> bitT[1024 bitpos][64 sgroup] u64 (LDS 64x64 transpose)
//  2. fused : block=(cn, QUARTER): rolling double-buffered NT stream of 64KB
//             (coalesced float4, 4-8 loads in flight) interleaved with addr
//             k-steps (scalar bitT loads + cndmask); ballot-pack to 2KB LDS
//             bit table; lookup 4096 addrs, ballot -> partial[cn][q][64].
//             2560 blocks (8 resident/CU + re-dispatch) de-clusters the
//             no-load phase windows across blocks.
//  3. reduce: OR 4 quarters, ballot-popcount over neurons -> out[4096][10]

#define BATCH   4096
#define ENTRY   1024
#define TUPLE   16
#define CLASSES 10
#define NEURONS 64
#define CN      (CLASSES * NEURONS)   // 640
#define ADDRSP  65536
#define QTR     (ADDRSP / 4)          // 16384 cells

typedef unsigned long long u64;
typedef unsigned int       u32;
typedef unsigned short     u16;
typedef float f32x4 __attribute__((ext_vector_type(4)));
typedef int   i32x4 __attribute__((ext_vector_type(4)));
typedef unsigned long long u64x2 __attribute__((ext_vector_type(2)));

// ---------------- Kernel 1: bit-transpose pack (coalesced, NT loads) ------
__global__ __launch_bounds__(256) void packT_kernel(
    const int* __restrict__ samples, u64* __restrict__ bitT)
{
    __shared__ int tile[64 * 65];
    const int sg   = blockIdx.x >> 4;
    const int cg   = blockIdx.x & 15;
    const int w    = threadIdx.x >> 6;
    const int lane = threadIdx.x & 63;
    const int t    = threadIdx.x;

#pragma unroll
    for (int rnd = 0; rnd < 4; ++rnd) {
        const int idx  = rnd * 256 + t;
        const int row  = idx >> 4;
        const int col4 = idx & 15;
        const i32x4 v = __builtin_nontemporal_load(
            reinterpret_cast<const i32x4*>(
                samples + (size_t)(sg * 64 + row) * ENTRY + cg * 64 + col4 * 4));
        int* tp = tile + row * 65 + col4 * 4;
        tp[0] = v.x; tp[1] = v.y; tp[2] = v.z; tp[3] = v.w;
    }
    __syncthreads();

#pragma unroll
    for (int k = 0; k < 16; ++k) {
        const int j = w * 16 + k;
        const u64 m = __ballot(tile[lane * 65 + j] & 1);
        if (lane == 0) bitT[(size_t)(cg * 64 + j) * 64 + sg] = m;
    }
}

// ---------------- Kernel 2: fused rolling stream + addr + lookup ----------
// grid 2560 blocks x 256 (8 resident/CU, wave-limited). block -> (cn, q).
__global__ __launch_bounds__(256) void fused_kernel(
    const int* __restrict__ tm, const float* __restrict__ ram,
    const u64* __restrict__ bitT, u64* __restrict__ partial)
{
    __shared__ u64 tbl[256];               // 2 KB: 16384-bit quarter table
    __shared__ u16 addrL[BATCH];           // 8 KB: this cn's 4096 addresses

    const int bid  = blockIdx.x;
    const int cn   = bid >> 2;
    const int q    = bid & 3;
    const int c    = cn >> 6;
    const int n    = cn & 63;
    const int tid  = threadIdx.x;
    const int lane = tid & 63;
    const int wu   = __builtin_amdgcn_readfirstlane(tid >> 6);

    // tuple indices for this (c,n): uniform -> s_load
    const int* tp = tm + c * ENTRY + n * TUPLE;
    int E[TUPLE];
#pragma unroll
    for (int tt = 0; tt < TUPLE; ++tt) E[tt] = tp[tt];

    const f32x4* rp = reinterpret_cast<const f32x4*>(
        ram + (size_t)cn * ADDRSP + q * QTR);

    // ---- Rolling pipeline: 4 chunks of 4 groups (group = 256 floats);
    //      issue chunk cc+1 before consuming chunk cc ----
    f32x4 buf[2][4];
#pragma unroll
    for (int j = 0; j < 4; ++j)
        buf[0][j] = __builtin_nontemporal_load(rp + (wu * 16 + j) * 64 + lane);

#pragma unroll
    for (int cc = 0; cc < 4; ++cc) {
        const int cur = cc & 1, nxt = cur ^ 1;
        if (cc < 3) {
#pragma unroll
            for (int j = 0; j < 4; ++j)
                buf[nxt][j] = __builtin_nontemporal_load(
                    rp + (wu * 16 + (cc + 1) * 4 + j) * 64 + lane);
        }
        // 4 addr k-steps (scalar loads, independent of vector loads)
#pragma unroll
        for (int kk = 0; kk < 4; ++kk) {
            const int sg = wu * 16 + cc * 4 + kk;     // uniform
            u32 a = 0;
#pragma unroll
            for (int tt = 0; tt < TUPLE; ++tt) {
                const u64 word = bitT[(size_t)E[tt] * 64 + sg];
                u32 bit;
                asm("v_cndmask_b32 %0, 0, 1, %1" : "=v"(bit) : "s"(word));
                a = (a << 1) | bit;
            }
            addrL[sg * 64 + lane] = (u16)a;
        }
        // consume chunk cc: ballot-pack to bit table (paired 16B LDS writes)
#pragma unroll
        for (int j = 0; j < 4; ++j) {
            const int g = wu * 16 + cc * 4 + j;
            const u64 m0 = __ballot(buf[cur][j].x != 0.0f);
            const u64 m1 = __ballot(buf[cur][j].y != 0.0f);
            const u64 m2 = __ballot(buf[cur][j].z != 0.0f);
            const u64 m3 = __ballot(buf[cur][j].w != 0.0f);
            if (lane == 0) {
                u64x2 lo; lo.x = m0; lo.y = m1;
                u64x2 hi; hi.x = m2; hi.y = m3;
                *reinterpret_cast<u64x2*>(&tbl[g * 4 + 0]) = lo;
                *reinterpret_cast<u64x2*>(&tbl[g * 4 + 2]) = hi;
            }
        }
    }
    __syncthreads();

    // ---- Phase C: lookup 4096 addresses against this quarter ----
    // bit of local float f: tbl[(f>>8)*4 + (f&3)] >> ((f>>2)&63)
    u64* pp = partial + (size_t)cn * 256 + q * 64;
#pragma unroll
    for (int i = 0; i < 16; ++i) {
        const u32 a     = addrL[wu * 1024 + i * 64 + lane];
        const u32 local = a & (QTR - 1);
        const u64 word  = tbl[(local >> 8) * 4 + (a & 3u)];
        u32 bit = (u32)(word >> ((local >> 2) & 63u)) & 1u;
        bit &= (u32)((a >> 14) == (u32)q);
        const u64 m = __ballot(bit != 0u);
        if (lane == 0) pp[wu * 16 + i] = m;
    }
}

// ---------------- Kernel 3: reduce ----------------
// 160 blocks x 256 = 640 waves. wave -> (class, sgroup); lane -> neuron.
__global__ __launch_bounds__(256) void reduce_kernel(
    const u64* __restrict__ partial, float* __restrict__ out)
{
    const int gid  = blockIdx.x * 4 + (threadIdx.x >> 6);  // 0..639
    const int lane = threadIdx.x & 63;
    const int c    = gid >> 6;
    const int sg   = gid & 63;

    const u64* pp = partial + ((size_t)(c * NEURONS + lane)) * 256 + sg;
    const u64 m = pp[0] | pp[64] | pp[128] | pp[192];

    float myv = 0.0f;
#pragma unroll
    for (int b2 = 0; b2 < 64; ++b2) {
        const u64 mb = __ballot((u32)(m >> b2) & 1u);
        if (lane == b2) myv = (float)__popcll(mb);
    }
    out[(sg * 64 + lane) * CLASSES + c] = myv;
}

extern "C" void kernel_launch(void* const* d_in, const int* in_sizes, int n_in,
                              void* d_out, int out_size, void* d_ws, size_t ws_size,
                              hipStream_t stream)
{
    const int*   samples = (const int*)d_in[0];
    const int*   tm      = (const int*)d_in[1];
    const float* ram     = (const float*)d_in[2];
    float*       out     = (float*)d_out;

    u64* bitT    = (u64*)d_ws;                              // 512 KB
    u64* partial = (u64*)((char*)d_ws + (512u << 10));      // 1.25 MB

    packT_kernel <<<1024, 256, 0, stream>>>(samples, bitT);
    fused_kernel <<<CN * 4, 256, 0, stream>>>(tm, ram, bitT, partial);
    reduce_kernel<<<CN / 4, 256, 0, stream>>>(partial, out);
}